// Round 14
// baseline (1123.096 us; speedup 1.0000x reference)
//
#include <hip/hip_runtime.h>

#define LL 4096
#define NB 4
#define NC 64
#define NT 4
#define NLAYERS 10
#define XS 5120   // padded x row stride (in l units; x is [B][C][XS][4])
#define XPAD 512  // left/right zero pad (>= max dilation)

typedef float v2f __attribute__((ext_vector_type(2)));

// ---------------- Threefry-2x32, key = (0, 42), 20 rounds ----------------
__device__ __forceinline__ void threefry2x32(unsigned x0, unsigned x1,
                                             unsigned& o0, unsigned& o1) {
  const unsigned ks0 = 0u, ks1 = 42u;
  const unsigned ks2 = 0x1BD11BDAu ^ ks0 ^ ks1;
  const unsigned ks[3] = {ks0, ks1, ks2};
  const unsigned r0[4] = {13u, 15u, 26u, 6u};
  const unsigned r1[4] = {17u, 29u, 16u, 24u};
  x0 += ks0; x1 += ks1;
#pragma unroll
  for (int g = 0; g < 5; ++g) {
    const unsigned* rr = (g & 1) ? r1 : r0;
#pragma unroll
    for (int j = 0; j < 4; ++j) {
      x0 += x1;
      unsigned r = rr[j];
      x1 = (x1 << r) | (x1 >> (32u - r));
      x1 ^= x0;
    }
    x0 += ks[(g + 1) % 3];
    x1 += ks[(g + 2) % 3] + (unsigned)(g + 1);
  }
  o0 = x0; o1 = x1;
}

__device__ __forceinline__ float u01(unsigned bits) {
  return __uint_as_float((bits >> 9) | 0x3f800000u) - 1.0f;
}

// LIF step: v = v + (x - v)/1.2 ; spike = v>=0.5 ; v *= (1-spike)
__device__ __forceinline__ float lif_step(float& v, float xt) {
  v = v + (xt - v) / 1.2f;
  float s = (v >= 0.5f) ? 1.0f : 0.0f;
  v = v * (1.0f - s);
  return s;
}

// ---------------- prep: transpose skip/res 1x1 + build wT ----------------
// skipT/resT: [i][c'][c]. wT: [i][g][ci][k][col16], col<8 gate co=g*8+col,
// col>=8 filt co=64+g*8+col-8.
__global__ void prep_kernel(const float* __restrict__ skip_w,
                            const float* __restrict__ res_w,
                            const float* __restrict__ conv_w,
                            float* __restrict__ skipT,
                            float* __restrict__ resT,
                            float* __restrict__ wT) {
  int i = blockIdx.x;
  for (int idx = threadIdx.x; idx < 4096; idx += 256) {
    int c = idx >> 6, cp = idx & 63;
    skipT[i * 4096 + cp * 64 + c] = skip_w[i * 4096 + c * 64 + cp];
    resT[i * 4096 + cp * 64 + c] = res_w[i * 4096 + c * 64 + cp];
  }
  for (int idx = threadIdx.x; idx < 8 * 64 * 3 * 16; idx += 256) {
    int col = idx & 15;
    int r = idx >> 4;
    int k = r % 3; r /= 3;
    int ci = r % 64;
    int g = r / 64;
    int co = (col < 8) ? (g * 8 + col) : (64 + g * 8 + (col - 8));
    wT[i * 24576 + idx] = conv_w[(i * 128 + co) * 192 + ci * 3 + k];
  }
}

// ---------------- diffusion-step embedding -> proj[i][b][c] ----------------
__global__ void proj_kernel(const int* __restrict__ dstep,
                            const float* __restrict__ w1, const float* __restrict__ b1,
                            const float* __restrict__ w2, const float* __restrict__ b2,
                            const float* __restrict__ pw, const float* __restrict__ pb,
                            float* __restrict__ proj) {
  __shared__ float e1[NB][NC];
  __shared__ float e2[NB][NC];
  int i = blockIdx.x;
  int tid = threadIdx.x;
  int b = tid >> 6, c = tid & 63;
  float d = (float)dstep[b];
  float v = d * w1[i * 64 + c] + b1[i * 64 + c];
  v = v / (1.0f + expf(-v));  // silu
  e1[b][c] = v;
  __syncthreads();
  float a = b2[i * 64 + c];
  for (int cp = 0; cp < 64; ++cp) a += e1[b][cp] * w2[(i * 64 + c) * 64 + cp];
  e2[b][c] = a;
  __syncthreads();
  float p = pb[i * 64 + c];
  for (int cp = 0; cp < 64; ++cp) p += e2[b][cp] * pw[(i * 64 + c) * 64 + cp];
  proj[(i * 4 + b) * 64 + c] = p;
}

// ---------------- per-(layer,b,co) proj-weighted tap sums S0,S1,S2 ----------------
__global__ void pc_kernel(const float* __restrict__ proj,
                          const float* __restrict__ conv_w,
                          float* __restrict__ pc) {
  __shared__ float pv[64];
  int layer = blockIdx.x, b = blockIdx.y;
  int tid = threadIdx.x;  // 128
  if (tid < 64) pv[tid] = proj[(layer * 4 + b) * 64 + tid];
  __syncthreads();
  int co = tid;
  const float* w = conv_w + (layer * 128 + co) * 192;
  float s0 = 0.0f, s1 = 0.0f, s2 = 0.0f;
  for (int ci = 0; ci < 64; ++ci) {
    float p = pv[ci];
    s0 += p * w[ci * 3 + 0];
    s1 += p * w[ci * 3 + 1];
    s2 += p * w[ci * 3 + 2];
  }
  float* o = pc + ((layer * 4 + b) * 128 + co) * 3;
  o[0] = s0; o[1] = s1; o[2] = s2;
}

// ---------------- zero the pad margins of x (ws is poisoned every call) ---------
__global__ void padzero_kernel(float* __restrict__ x) {
  int row = blockIdx.x;  // 256 rows = B*C
  float* base = x + (size_t)row * XS * 4;
  for (int i = threadIdx.x; i < XPAD; i += 256) {
    *(float4*)&base[i * 4] = float4{0.f, 0.f, 0.f, 0.f};
    *(float4*)&base[(XPAD + LL + i) * 4] = float4{0.f, 0.f, 0.f, 0.f};
  }
}

// ---------------- Poisson encode + input conv + LIF -> x [B][C][XS][4] ---------
__global__ void encode_lif_kernel(const float* __restrict__ audio,
                                  const float* __restrict__ W_in,
                                  const float* __restrict__ b_in,
                                  float* __restrict__ x) {
  int tid = threadIdx.x;
  int lq = tid & 63, grp = tid >> 6;
  int l = blockIdx.x * 64 + lq;
  int b = blockIdx.y;
  float a = audio[b * LL + l];
  unsigned p0 = (unsigned)(b * LL + l);  // t=0 (o0), t=2 (o1)
  unsigned p1 = 16384u + p0;             // t=1 (o0), t=3 (o1)
  unsigned o00, o01, o10, o11;
  threefry2x32(p0, p0 + 32768u, o00, o01);
  threefry2x32(p1, p1 + 32768u, o10, o11);
  float sp[4];
  sp[0] = (u01(o00) < a) ? 1.0f : 0.0f;
  sp[1] = (u01(o10) < a) ? 1.0f : 0.0f;
  sp[2] = (u01(o01) < a) ? 1.0f : 0.0f;
  sp[3] = (u01(o11) < a) ? 1.0f : 0.0f;
  for (int j = 0; j < 16; ++j) {
    int c = grp * 16 + j;
    float w = W_in[c], bb = b_in[c];
    float v = 0.0f;
    float4 o;
    float* op = (float*)&o;
#pragma unroll
    for (int t = 0; t < 4; ++t) op[t] = lif_step(v, w * sp[t] + bb);
    *(float4*)&x[(size_t)((b * 64 + c) * XS + XPAD + l) * 4] = o;
  }
}

// ---------------- dilated conv + LIF + gate -> y [B][LL][64][4] (l-major!) ------
// grid (16, 8, 4): l-tile 256, co-group g, b. block 256. R12 structure
// verbatim (best measured: all weights global-uniform, x 3 float4/ci,
// 2-deep prefetch, no LDS). Only the y STORE index changes: y l-major so
// skip_res can stream it. Each thread writes 8 co x 16 B = one aligned
// 128-B line per l (thread-owned, no cross-block sharing).
template <int DIL>
__global__ __launch_bounds__(256) void layer_conv_kernel(
    const float* __restrict__ x, const float* __restrict__ wT,
    const float* __restrict__ conv_b, const float* __restrict__ pc,
    float* __restrict__ y, int layer) {
  int tid = threadIdx.x;
  int g = blockIdx.y;
  int b = blockIdx.z;
  int l = blockIdx.x * 256 + tid;
  const float* wbase = wT + (size_t)(layer * 8 + g) * 3072;  // [ci*3+k][col16]

  const float* px = x + (size_t)(b * 64 * XS + XPAD + l) * 4;  // ci=0 row

  v2f ag[16], af[16];  // [t*4 + pair], pair p covers co j=2p,2p+1
#pragma unroll
  for (int q = 0; q < 16; ++q) {
    ag[q] = (v2f)(0.0f);
    af[q] = (v2f)(0.0f);
  }

  float4 xa[3], xb[3];  // [k] = 4 t values
  auto loadx = [&](float4* dst) {
    dst[0] = *(const float4*)(px - (size_t)DIL * 4);
    dst[1] = *(const float4*)px;
    dst[2] = *(const float4*)(px + (size_t)DIL * 4);
    px += (size_t)XS * 4;
  };
  auto compute = [&](int ci, const float4* xv) {
#pragma unroll
    for (int k = 0; k < 3; ++k) {
      const v2f* wr = (const v2f*)&wbase[(ci * 3 + k) * 16];
      v2f g0 = wr[0], g1 = wr[1], g2 = wr[2], g3 = wr[3];
      v2f f0 = wr[4], f1 = wr[5], f2 = wr[6], f3 = wr[7];
      const float* xk = (const float*)&xv[k];
#pragma unroll
      for (int t = 0; t < 4; ++t) {
        float xq = xk[t];
        v2f x2;
        x2.x = xq; x2.y = xq;
        ag[t * 4 + 0] += g0 * x2;
        ag[t * 4 + 1] += g1 * x2;
        ag[t * 4 + 2] += g2 * x2;
        ag[t * 4 + 3] += g3 * x2;
        af[t * 4 + 0] += f0 * x2;
        af[t * 4 + 1] += f1 * x2;
        af[t * 4 + 2] += f2 * x2;
        af[t * 4 + 3] += f3 * x2;
      }
    }
  };

  loadx(xa);
  for (int ci = 0; ci < 64; ci += 2) {
    loadx(xb);
    compute(ci, xa);
    if (ci + 2 < 64) loadx(xa);
    compute(ci + 1, xb);
  }

  const float SIG1 = 0.73105857863000489f;   // sigmoid(1) fp32
  const float TANH1 = 0.76159415595576486f;  // tanh(1) fp32
  bool lb = (l < DIL), rb = (l >= LL - DIL);
#pragma unroll
  for (int j = 0; j < 8; ++j) {
    int cog = g * 8 + j;
    int cof = 64 + g * 8 + j;
    const float* pg = pc + ((layer * 4 + b) * 128 + cog) * 3;
    const float* pf = pc + ((layer * 4 + b) * 128 + cof) * 3;
    float S0g = pg[0], S1g = pg[1], S2g = pg[2];
    float S0f = pf[0], S1f = pf[1], S2f = pf[2];
    float bg = conv_b[layer * 128 + cog] + S0g + S1g + S2g;
    float bf = conv_b[layer * 128 + cof] + S0f + S1f + S2f;
    bg -= (lb ? S0g : 0.0f) + (rb ? S2g : 0.0f);
    bf -= (lb ? S0f : 0.0f) + (rb ? S2f : 0.0f);
    float vg = 0.0f, vf = 0.0f;
    float4 o;
    float* op = (float*)&o;
#pragma unroll
    for (int t = 0; t < 4; ++t) {
      float av = ag[t * 4 + (j >> 1)][j & 1];
      float fv = af[t * 4 + (j >> 1)][j & 1];
      float sg = lif_step(vg, av + bg);
      float sf = lif_step(vf, fv + bf);
      float gv = (sg != 0.0f) ? SIG1 : 0.5f;
      float tv = (sf != 0.0f) ? TANH1 : 0.0f;
      op[t] = gv * tv;
    }
    // l-major store: y[b][l][cog][t]
    *(float4*)&y[(size_t)((b * LL + l) * 64 + cog) * 4] = o;
  }
}

// ---------------- fused 1x1 skip + res convs (shared y loads) ----------------
// grid (128, 4): l-tile 32, b. block 256 = 16 lg (2 l) x 16 cg (4 c).
// Thread: 4 c x 2 l x 4 t for BOTH convs (64 acc floats). y is l-major:
// the cp loop walks 16 B contiguous per l-stream (L1-friendly), 1-deep
// prefetch. w loads uniform. Sequential cp order -> per-conv sums
// bit-identical to previous rounds.
__global__ __launch_bounds__(256) void skip_res_kernel(
    const float* __restrict__ y, const float* __restrict__ skipT,
    const float* __restrict__ resT, const float* __restrict__ skip_b,
    const float* __restrict__ res_b, float* __restrict__ tskip,
    float* __restrict__ x, int layer) {
  int tid = threadIdx.x;
  int lg = tid & 15;   // 16 l-groups of 2
  int cg = tid >> 4;   // 16 c-groups of 4
  int b = blockIdx.y;
  int l0 = blockIdx.x * 32 + lg * 2;
  int c0 = cg * 4;

  const float* wS = skipT + layer * 4096 + c0;  // [cp][c]
  const float* wR = resT + layer * 4096 + c0;
  const float* yb = y + (size_t)(b * LL + l0) * 64 * 4;  // row l0; +256 = l0+1

  v2f aS[16], aR[16];  // [c4][l2][t-pair2]
#pragma unroll
  for (int q = 0; q < 16; ++q) { aS[q] = (v2f)(0.0f); aR[q] = (v2f)(0.0f); }

  float4 wSa = *(const float4*)&wS[0];
  float4 wRa = *(const float4*)&wR[0];
  float4 y0a = *(const float4*)&yb[0];    // l0,  cp=0, t0..3
  float4 y1a = *(const float4*)&yb[256];  // l0+1, cp=0, t0..3

  for (int cp = 0; cp < 64; ++cp) {
    int cpn = (cp < 63) ? cp + 1 : 63;
    float4 wSb = *(const float4*)&wS[cpn * 64];
    float4 wRb = *(const float4*)&wR[cpn * 64];
    float4 y0b = *(const float4*)&yb[cpn * 4];
    float4 y1b = *(const float4*)&yb[256 + cpn * 4];

    float sv[4] = {wSa.x, wSa.y, wSa.z, wSa.w};
    float rv[4] = {wRa.x, wRa.y, wRa.z, wRa.w};
    const v2f* yp0 = (const v2f*)&y0a;  // t01, t23
    const v2f* yp1 = (const v2f*)&y1a;
#pragma unroll
    for (int i = 0; i < 4; ++i) {
      v2f s2, r2;
      s2.x = sv[i]; s2.y = sv[i];
      r2.x = rv[i]; r2.y = rv[i];
      aS[i * 4 + 0] += s2 * yp0[0];
      aS[i * 4 + 1] += s2 * yp0[1];
      aS[i * 4 + 2] += s2 * yp1[0];
      aS[i * 4 + 3] += s2 * yp1[1];
      aR[i * 4 + 0] += r2 * yp0[0];
      aR[i * 4 + 1] += r2 * yp0[1];
      aR[i * 4 + 2] += r2 * yp1[0];
      aR[i * 4 + 3] += r2 * yp1[1];
    }
    wSa = wSb; wRa = wRb; y0a = y0b; y1a = y1b;
  }

#pragma unroll
  for (int i = 0; i < 4; ++i) {
    int c = c0 + i;
    float sbb = skip_b[layer * 64 + c];
    float rbb = res_b[layer * 64 + c];
    // skip -> tskip (l-major): [b][l][c][4]
#pragma unroll
    for (int dl = 0; dl < 2; ++dl) {
      v2f p01 = aS[i * 4 + dl * 2 + 0];
      v2f p23 = aS[i * 4 + dl * 2 + 1];
      size_t idx = ((size_t)(b * LL + l0 + dl) * 64 + c) * 4;
      float4 o;
      if (layer == 0) o = float4{0.f, 0.f, 0.f, 0.f};
      else o = *(const float4*)&tskip[idx];
      o.x += p01[0] + sbb; o.y += p01[1] + sbb;
      o.z += p23[0] + sbb; o.w += p23[1] + sbb;
      *(float4*)&tskip[idx] = o;
    }
    // res -> x (c-major): [b][c][XS][4]
#pragma unroll
    for (int dl = 0; dl < 2; ++dl) {
      v2f p01 = aR[i * 4 + dl * 2 + 0];
      v2f p23 = aR[i * 4 + dl * 2 + 1];
      size_t idx = ((size_t)(b * 64 + c) * XS + XPAD + l0 + dl) * 4;
      float4 o = *(const float4*)&x[idx];
      o.x += p01[0] + rbb; o.y += p01[1] + rbb;
      o.z += p23[0] + rbb; o.w += p23[1] + rbb;
      *(float4*)&x[idx] = o;
    }
  }
}

// ---------------- output conv + LIF + sum over T (tskip l-major) -------------
__global__ void out_kernel(const float* __restrict__ tskip,
                           const float* __restrict__ W_out,
                           const float* __restrict__ b_out,
                           float* __restrict__ out) {
  __shared__ float red[4][4][64];  // [grp][t][lq]
  int tid = threadIdx.x;
  int lq = tid & 63, grp = tid >> 6;
  int l = blockIdx.x * 64 + lq;
  int b = blockIdx.y;
  float acc[4] = {0.0f, 0.0f, 0.0f, 0.0f};
  for (int j = 0; j < 16; ++j) {
    int c = grp * 16 + j;
    float w = W_out[c];
    float4 sv = *(const float4*)&tskip[(size_t)((b * LL + l) * 64 + c) * 4];
    acc[0] += fmaxf(sv.x, 0.0f) * w;
    acc[1] += fmaxf(sv.y, 0.0f) * w;
    acc[2] += fmaxf(sv.z, 0.0f) * w;
    acc[3] += fmaxf(sv.w, 0.0f) * w;
  }
#pragma unroll
  for (int t = 0; t < 4; ++t) red[grp][t][lq] = acc[t];
  __syncthreads();
  if (grp == 0) {
    float bo = b_out[0];
    float v = 0.0f, s = 0.0f;
#pragma unroll
    for (int t = 0; t < 4; ++t) {
      float a = red[0][t][lq] + red[1][t][lq] + red[2][t][lq] + red[3][t][lq] + bo;
      s += lif_step(v, a);
    }
    out[b * LL + l] = s;
  }
}

extern "C" void kernel_launch(void* const* d_in, const int* in_sizes, int n_in,
                              void* d_out, int out_size, void* d_ws, size_t ws_size,
                              hipStream_t stream) {
  const float* audio   = (const float*)d_in[0];
  const int*   dstep   = (const int*)d_in[1];
  const float* W_in    = (const float*)d_in[2];
  const float* b_in    = (const float*)d_in[3];
  const float* demb_w1 = (const float*)d_in[4];
  const float* demb_b1 = (const float*)d_in[5];
  const float* demb_w2 = (const float*)d_in[6];
  const float* demb_b2 = (const float*)d_in[7];
  const float* dproj_w = (const float*)d_in[8];
  const float* dproj_b = (const float*)d_in[9];
  const float* conv_w  = (const float*)d_in[10];
  const float* conv_b  = (const float*)d_in[11];
  const float* skip_w  = (const float*)d_in[12];
  const float* skip_b  = (const float*)d_in[13];
  const float* res_w   = (const float*)d_in[14];
  const float* res_b   = (const float*)d_in[15];
  const float* W_out   = (const float*)d_in[16];
  const float* b_out   = (const float*)d_in[17];
  float* out = (float*)d_out;
  float* ws = (float*)d_ws;

  float* proj  = ws;                   // 2560
  float* skipT = proj + 2560;          // 40960
  float* resT  = skipT + 40960;        // 40960
  float* pc    = resT + 40960;         // 15360
  float* wT    = pc + 15360;           // 10*8*64*48 = 245760
  float* x     = wT + 245760;          // 4*64*5120*4 = 5242880
  float* y     = x + 5242880;          // 4*4096*64*4 = 4194304 (l-major)
  float* tskip = y + 4194304;          // 4194304 (l-major)

  prep_kernel<<<10, 256, 0, stream>>>(skip_w, res_w, conv_w, skipT, resT, wT);
  proj_kernel<<<10, 256, 0, stream>>>(dstep, demb_w1, demb_b1, demb_w2, demb_b2,
                                      dproj_w, dproj_b, proj);
  pc_kernel<<<dim3(10, 4), 128, 0, stream>>>(proj, conv_w, pc);
  padzero_kernel<<<256, 256, 0, stream>>>(x);
  encode_lif_kernel<<<dim3(64, 4), 256, 0, stream>>>(audio, W_in, b_in, x);

  for (int i = 0; i < NLAYERS; ++i) {
    dim3 gc(16, 8, 4);
    switch (i) {
      case 0: layer_conv_kernel<1><<<gc, 256, 0, stream>>>(x, wT, conv_b, pc, y, i); break;
      case 1: layer_conv_kernel<2><<<gc, 256, 0, stream>>>(x, wT, conv_b, pc, y, i); break;
      case 2: layer_conv_kernel<4><<<gc, 256, 0, stream>>>(x, wT, conv_b, pc, y, i); break;
      case 3: layer_conv_kernel<8><<<gc, 256, 0, stream>>>(x, wT, conv_b, pc, y, i); break;
      case 4: layer_conv_kernel<16><<<gc, 256, 0, stream>>>(x, wT, conv_b, pc, y, i); break;
      case 5: layer_conv_kernel<32><<<gc, 256, 0, stream>>>(x, wT, conv_b, pc, y, i); break;
      case 6: layer_conv_kernel<64><<<gc, 256, 0, stream>>>(x, wT, conv_b, pc, y, i); break;
      case 7: layer_conv_kernel<128><<<gc, 256, 0, stream>>>(x, wT, conv_b, pc, y, i); break;
      case 8: layer_conv_kernel<256><<<gc, 256, 0, stream>>>(x, wT, conv_b, pc, y, i); break;
      case 9: layer_conv_kernel<512><<<gc, 256, 0, stream>>>(x, wT, conv_b, pc, y, i); break;
    }
    skip_res_kernel<<<dim3(128, 4), 256, 0, stream>>>(y, skipT, resT, skip_b,
                                                      res_b, tskip, x, i);
  }
  out_kernel<<<dim3(64, 4), 256, 0, stream>>>(tskip, W_out, b_out, out);
}